// Round 1
// baseline (17885.378 us; speedup 1.0000x reference)
//
#include <hip/hip_runtime.h>
#include <math.h>

typedef _Float16 f16;
typedef __attribute__((__ext_vector_type__(8))) _Float16 f16x8;
typedef __attribute__((__ext_vector_type__(4))) float f32x4;

static __device__ __forceinline__ f32x4 mfma16(f16x8 a, f16x8 b, f32x4 c) {
  return __builtin_amdgcn_mfma_f32_16x16x32_f16(a, b, c, 0, 0, 0);
}
static __device__ __forceinline__ float sigf(float x) { return 1.0f / (1.0f + expf(-x)); }
static __device__ __forceinline__ void split2(float v, f16* hi, f16* lo) {
  f16 h = (f16)v;
  *hi = h;
  *lo = (f16)((v - (float)h) * 2048.0f);  // scaled lo-plane: avoids f16 denormal flush
}

// ---------------- fp32 -> f16 hi/lo planes (row padding cs->cd with zeros) ---------
__global__ void k_split(const float* __restrict__ src, f16* __restrict__ hi,
                        f16* __restrict__ lo, int cs, int cd, long total) {
  for (long i = (long)blockIdx.x * 256 + threadIdx.x; i < total; i += (long)gridDim.x * 256) {
    int r = (int)(i / cd), c = (int)(i % cd);
    float v = (c < cs) ? src[(long)r * cs + c] : 0.0f;
    split2(v, &hi[i], &lo[i]);
  }
}

// ---------------- embedding gather + split (rows of 300 padded to 320) -------------
__global__ void k_gather(const int* __restrict__ idx, const float* __restrict__ tab,
                         f16* __restrict__ hi, f16* __restrict__ lo, long total) {
  for (long i = (long)blockIdx.x * 256 + threadIdx.x; i < total; i += (long)gridDim.x * 256) {
    int r = (int)(i / 320), c = (int)(i % 320);
    float v = (c < 300) ? tab[(long)idx[r] * 300 + c] : 0.0f;
    split2(v, &hi[i], &lo[i]);
  }
}

// ---------------- split-f16 GEMM: C[M,N] = A[M,K] @ B[N,K]^T (+bias) --------------
// A,B given as hi/lo f16 planes (lo pre-scaled x2048). BN=128, BK=64.
template <int BM>
__global__ __launch_bounds__(256, 1) void k_gemm(
    const f16* __restrict__ Ahi, const f16* __restrict__ Alo,
    const f16* __restrict__ Bhi, const f16* __restrict__ Blo,
    const float* __restrict__ bias, float* __restrict__ C,
    int M, int N, int K, long aB, long bB, long cB) {
  constexpr int MF = (BM == 128) ? 4 : 2;
  constexpr int NF = (BM == 128) ? 4 : 2;
  __shared__ f16 sA[2][BM][72];
  __shared__ f16 sB[2][128][72];

  const int tid = threadIdx.x;
  const int wid = tid >> 6, lane = tid & 63;
  const int ln = lane & 15, l4 = lane >> 4;
  const int m0 = blockIdx.y * BM;
  const int n0 = blockIdx.x * 128;
  const int z = blockIdx.z;
  const f16* pAh = Ahi + (long)z * aB;
  const f16* pAl = Alo + (long)z * aB;
  const f16* pBh = Bhi + (long)z * bB;
  const f16* pBl = Blo + (long)z * bB;
  float* pC = C + (long)z * cB;

  const int wrow = (BM == 128) ? (wid >> 1) * 64 : 0;
  const int wcol = (BM == 128) ? (wid & 1) * 64 : wid * 32;

  f32x4 am[MF][NF], ax[MF][NF];
#pragma unroll
  for (int i = 0; i < MF; ++i)
#pragma unroll
    for (int j = 0; j < NF; ++j) {
      am[i][j] = (f32x4){0.f, 0.f, 0.f, 0.f};
      ax[i][j] = (f32x4){0.f, 0.f, 0.f, 0.f};
    }

  for (int k0 = 0; k0 < K; k0 += 64) {
#pragma unroll
    for (int p = 0; p < 2; ++p) {
      const f16* sa = p ? pAl : pAh;
      for (int i = tid; i < BM * 8; i += 256) {
        int r = i >> 3, ch = i & 7;
        uint4 v = make_uint4(0u, 0u, 0u, 0u);
        int gr = m0 + r;
        if (gr < M) v = *(const uint4*)(sa + (long)gr * K + k0 + ch * 8);
        *(uint4*)&sA[p][r][ch * 8] = v;
      }
      const f16* sb = p ? pBl : pBh;
      for (int i = tid; i < 1024; i += 256) {
        int r = i >> 3, ch = i & 7;
        uint4 v = make_uint4(0u, 0u, 0u, 0u);
        int gn = n0 + r;
        if (gn < N) v = *(const uint4*)(sb + (long)gn * K + k0 + ch * 8);
        *(uint4*)&sB[p][r][ch * 8] = v;
      }
    }
    __syncthreads();
#pragma unroll
    for (int kk = 0; kk < 64; kk += 32) {
      const int kc = kk + l4 * 8;
      f16x8 ah[MF], al[MF], bh[NF], bl[NF];
#pragma unroll
      for (int i = 0; i < MF; ++i) {
        ah[i] = *(const f16x8*)&sA[0][wrow + i * 16 + ln][kc];
        al[i] = *(const f16x8*)&sA[1][wrow + i * 16 + ln][kc];
      }
#pragma unroll
      for (int j = 0; j < NF; ++j) {
        bh[j] = *(const f16x8*)&sB[0][wcol + j * 16 + ln][kc];
        bl[j] = *(const f16x8*)&sB[1][wcol + j * 16 + ln][kc];
      }
#pragma unroll
      for (int i = 0; i < MF; ++i)
#pragma unroll
        for (int j = 0; j < NF; ++j) {
          am[i][j] = mfma16(ah[i], bh[j], am[i][j]);
          ax[i][j] = mfma16(ah[i], bl[j], ax[i][j]);
          ax[i][j] = mfma16(al[i], bh[j], ax[i][j]);
        }
    }
    __syncthreads();
  }
#pragma unroll
  for (int i = 0; i < MF; ++i)
#pragma unroll
    for (int j = 0; j < NF; ++j) {
      int row = m0 + wrow + i * 16 + l4 * 4;
      int col = n0 + wcol + j * 16 + ln;
      if (col < N) {
        float bv = bias ? bias[col] : 0.0f;
#pragma unroll
        for (int r = 0; r < 4; ++r)
          if (row + r < M)
            pC[(long)(row + r) * N + col] = am[i][j][r] + ax[i][j][r] * (1.0f / 2048.0f) + bv;
      }
    }
}

// ---------------- persistent bidirectional LSTM layer ------------------------------
// grid = 64 WGs (2 dirs x 32). Each WG owns 16 h-columns (j0 = wg*16); its Whh slice
// (4 gates x 16 cols x K=512, hi+lo) lives in LDS. h is broadcast via global ping-pong
// planes; one device-scope barrier per timestep; c-state in registers.
__global__ __launch_bounds__(256, 1) void k_lstm(
    const f16* __restrict__ WhhHi, const f16* __restrict__ WhhLo,  // [2][2048][512]
    const float* __restrict__ Gx,                                  // [S*32][4096]
    f16* __restrict__ hHi, f16* __restrict__ hLo,                  // [2par][2dir][32][512]
    f16* __restrict__ oHi, f16* __restrict__ oLo,                  // [S*32][1024] or null
    float* __restrict__ hidOut, float* __restrict__ cOut,          // [4][32][512]
    unsigned* __restrict__ bar, int S, int layer) {
  const int tid = threadIdx.x;
  const int d = blockIdx.x >> 5;
  const int wg = blockIdx.x & 31;
  const int j0 = wg * 16;

  __shared__ f16 sWh[64][520];
  __shared__ f16 sWl[64][520];
  __shared__ float sGate[2][4][32][16];
  __shared__ float sGx[32][64];

  for (int p = 0; p < 2; ++p) {
    const f16* W = p ? WhhLo : WhhHi;
    for (int i = tid; i < 64 * 64; i += 256) {
      int r = i >> 6, ch = i & 63;
      int g = r >> 4, jj = r & 15;
      const f16* srcp = W + (((long)d * 2048 + g * 512 + j0 + jj) << 9) + ch * 8;
      uint4 v = *(const uint4*)srcp;
      if (p) *(uint4*)&sWl[r][ch * 8] = v;
      else   *(uint4*)&sWh[r][ch * 8] = v;
    }
  }
  __syncthreads();

  const int wid = tid >> 6, lane = tid & 63;
  const int gh = wid & 1, kh = wid >> 1;
  const int ln = lane & 15, lk8 = (lane >> 4) * 8;

  float creg[2] = {0.0f, 0.0f};
  unsigned calls = 0;

  for (int t = 0; t < S; ++t) {
    const int trow = d ? (S - 1 - t) : t;
    const int par = t & 1;

    // prefetch this step's Gx slice into regs
    float4 gx[2];
#pragma unroll
    for (int q = 0; q < 2; ++q) {
      int i = tid + q * 256;
      int b = i >> 4, c4 = i & 15;
      int g = c4 >> 2, f4 = c4 & 3;
      gx[q] = *(const float4*)&Gx[((long)trow * 32 + b) * 4096 + (long)d * 2048 + g * 512 + j0 + f4 * 4];
    }

    // recurrent GEMM: gates[b][g*16+jj] partial (gates 2gh..2gh+1, k-half kh)
    f32x4 am[2][2], ax[2][2];
#pragma unroll
    for (int a = 0; a < 2; ++a)
#pragma unroll
      for (int b2 = 0; b2 < 2; ++b2) {
        am[a][b2] = (f32x4){0.f, 0.f, 0.f, 0.f};
        ax[a][b2] = (f32x4){0.f, 0.f, 0.f, 0.f};
      }
    const f16* hRh = hHi + ((long)par * 2 + d) * 32 * 512;
    const f16* hRl = hLo + ((long)par * 2 + d) * 32 * 512;
#pragma unroll
    for (int ks = kh * 8; ks < kh * 8 + 8; ++ks) {
      const int kc = ks * 32 + lk8;
      f16x8 a0h = *(const f16x8*)&hRh[(0 + ln) * 512 + kc];
      f16x8 a1h = *(const f16x8*)&hRh[(16 + ln) * 512 + kc];
      f16x8 a0l = *(const f16x8*)&hRl[(0 + ln) * 512 + kc];
      f16x8 a1l = *(const f16x8*)&hRl[(16 + ln) * 512 + kc];
#pragma unroll
      for (int gl = 0; gl < 2; ++gl) {
        const int g = gh * 2 + gl;
        f16x8 bh = *(const f16x8*)&sWh[g * 16 + ln][kc];
        f16x8 bl = *(const f16x8*)&sWl[g * 16 + ln][kc];
        am[gl][0] = mfma16(a0h, bh, am[gl][0]);
        ax[gl][0] = mfma16(a0h, bl, ax[gl][0]);
        ax[gl][0] = mfma16(a0l, bh, ax[gl][0]);
        am[gl][1] = mfma16(a1h, bh, am[gl][1]);
        ax[gl][1] = mfma16(a1h, bl, ax[gl][1]);
        ax[gl][1] = mfma16(a1l, bh, ax[gl][1]);
      }
    }

    // deposit Gx + partial gates to LDS
#pragma unroll
    for (int q = 0; q < 2; ++q) {
      int i = tid + q * 256;
      int b = i >> 4, c4 = i & 15;
      *(float4*)&sGx[b][c4 * 4] = gx[q];
    }
#pragma unroll
    for (int gl = 0; gl < 2; ++gl) {
      const int g = gh * 2 + gl;
#pragma unroll
      for (int mf = 0; mf < 2; ++mf) {
        const int row = mf * 16 + (lane >> 4) * 4;
#pragma unroll
        for (int r = 0; r < 4; ++r)
          sGate[kh][g][row + r][ln] = am[gl][mf][r] + ax[gl][mf][r] * (1.0f / 2048.0f);
      }
    }
    __syncthreads();

    // elementwise cell update for owned 16 columns (2 elems/thread), c stays in regs
#pragma unroll
    for (int q = 0; q < 2; ++q) {
      int e = tid + q * 256;
      int b = e >> 4, jj = e & 15;
      float iv = sGate[0][0][b][jj] + sGate[1][0][b][jj] + sGx[b][jj];
      float fv = sGate[0][1][b][jj] + sGate[1][1][b][jj] + sGx[b][16 + jj];
      float gv = sGate[0][2][b][jj] + sGate[1][2][b][jj] + sGx[b][32 + jj];
      float ov = sGate[0][3][b][jj] + sGate[1][3][b][jj] + sGx[b][48 + jj];
      float c_ = sigf(fv) * creg[q] + sigf(iv) * tanhf(gv);
      creg[q] = c_;
      float h_ = sigf(ov) * tanhf(c_);
      f16 hh, hl;
      split2(h_, &hh, &hl);
      long ho = (((long)(par ^ 1) * 2 + d) * 32 + b) * 512 + j0 + jj;
      hHi[ho] = hh;
      hLo[ho] = hl;
      if (oHi) {
        long oo = ((long)trow * 32 + b) * 1024 + (long)d * 512 + j0 + jj;
        oHi[oo] = hh;
        oLo[oo] = hl;
      }
      if (t == S - 1) {
        long so = (((long)layer * 2 + d) * 32 + b) * 512 + j0 + jj;
        hidOut[so] = h_;
        cOut[so] = c_;
      }
    }

    // device-scope barrier (all 64 WGs; guaranteed co-resident: 64 WGs, 1/CU, 256 CUs)
    __threadfence();
    __syncthreads();
    if (tid == 0) {
      __hip_atomic_fetch_add(bar, 1u, __ATOMIC_ACQ_REL, __HIP_MEMORY_SCOPE_AGENT);
      ++calls;
      unsigned tgt = calls * 64u;
      while (__hip_atomic_load(bar, __ATOMIC_ACQUIRE, __HIP_MEMORY_SCOPE_AGENT) < tgt)
        __builtin_amdgcn_s_sleep(2);
    }
    __syncthreads();
  }
}

// ---------------- VAE elementwise ---------------------------------------------------
__global__ void k_vae(const float* __restrict__ mu, const float* __restrict__ lv,
                      const float* __restrict__ zn, float* __restrict__ outMu,
                      float* __restrict__ outLv, float* __restrict__ outZ,
                      f16* __restrict__ zHi, f16* __restrict__ zLo) {
  int i = blockIdx.x * 256 + threadIdx.x;
  if (i >= 4 * 32 * 512) return;
  int bj = i & (32 * 512 - 1);
  float m = mu[i], l = lv[i];
  float z = zn[bj] * expf(0.5f * l) + m;
  outMu[i] = m;
  outLv[i] = l;
  outZ[i] = z;
  split2(z, &zHi[i], &zLo[i]);
}

// ---------------- decoder init ------------------------------------------------------
__global__ void k_decinit(const float* __restrict__ hInit, const float* __restrict__ cEnc,
                          const int* __restrict__ summary, f16* __restrict__ dhHi,
                          f16* __restrict__ dhLo, float* __restrict__ cDec,
                          int* __restrict__ tok) {
  int i = blockIdx.x * 256 + threadIdx.x;
  if (i < 4 * 32 * 512) {
    split2(hInit[i], &dhHi[i], &dhLo[i]);
    cDec[i] = cEnc[i];
  }
  if (i < 32) tok[i] = summary[i];  // summary[0][b]
}

// ---------------- decoder LSTM cell elementwise -------------------------------------
__global__ void k_cell(const float* __restrict__ Gd, const float* __restrict__ Hd,
                       float* __restrict__ cDec, f16* __restrict__ dhHi,
                       f16* __restrict__ dhLo, f16* __restrict__ xHi,
                       f16* __restrict__ xLo, int layer) {
  int i = blockIdx.x * 256 + threadIdx.x;
  if (i >= 2 * 32 * 512) return;
  int d = i >> 14, b = (i >> 9) & 31, j = i & 511;
  long gb = (long)b * 4096 + d * 2048 + j;
  long hb = ((long)d * 32 + b) * 2048 + j;
  float iv = Gd[gb] + Hd[hb];
  float fv = Gd[gb + 512] + Hd[hb + 512];
  float gv = Gd[gb + 1024] + Hd[hb + 1024];
  float ov = Gd[gb + 1536] + Hd[hb + 1536];
  long so = (((long)layer * 2 + d) * 32 + b) * 512 + j;
  float c_ = sigf(fv) * cDec[so] + sigf(iv) * tanhf(gv);
  cDec[so] = c_;
  float h_ = sigf(ov) * tanhf(c_);
  f16 hh, hl;
  split2(h_, &hh, &hl);
  dhHi[so] = hh;
  dhLo[so] = hl;
  long xo = (long)b * 1024 + d * 512 + j;
  xHi[xo] = hh;
  xLo[xo] = hl;
}

// ---------------- fused log-softmax + argmax (one WG per batch row) -----------------
__global__ __launch_bounds__(256) void k_lsm(const float* __restrict__ logits,
                                             float* __restrict__ outs,
                                             int* __restrict__ tok, int t) {
  const int b = blockIdx.x;
  const int tid = threadIdx.x;
  const float* lg = logits + (long)b * 50000;
  float m = -INFINITY, s = 0.0f;
  int am = 0;
  for (int v = tid; v < 50000; v += 256) {
    float x = lg[v];
    if (x > m) {
      s = s * expf(m - x) + 1.0f;
      m = x;
      am = v;
    } else {
      s += expf(x - m);
    }
  }
  __shared__ float sm[256], ss[256];
  __shared__ int sa[256];
  sm[tid] = m; ss[tid] = s; sa[tid] = am;
  __syncthreads();
  for (int o = 128; o > 0; o >>= 1) {
    if (tid < o) {
      float m2 = sm[tid + o], s2 = ss[tid + o];
      int a2 = sa[tid + o];
      float m1 = sm[tid], s1 = ss[tid];
      int a1 = sa[tid];
      if (m2 > m1 || (m2 == m1 && a2 < a1)) {
        sm[tid] = m2; ss[tid] = s2 + s1 * expf(m1 - m2); sa[tid] = a2;
      } else {
        ss[tid] = s1 + s2 * expf(m2 - m1);
      }
    }
    __syncthreads();
  }
  float lse = sm[0] + logf(ss[0]);
  float* ob = outs + ((long)t * 32 + b) * 50000;
  for (int v = tid; v < 50000; v += 256) ob[v] = lg[v] - lse;
  if (tid == 0) tok[b] = sa[0];
}

// ====================================================================================
extern "C" void kernel_launch(void* const* d_in, const int* in_sizes, int n_in,
                              void* d_out, int out_size, void* d_ws, size_t ws_size,
                              hipStream_t stream) {
  const int* article = (const int*)d_in[0];
  const int* summary = (const int*)d_in[1];
  const float* z_noise = (const float*)d_in[2];
  const float* enc_emb = (const float*)d_in[3];
  const float* e0Wih = (const float*)d_in[4];
  const float* e0Whh = (const float*)d_in[5];
  const float* e0b = (const float*)d_in[6];
  const float* e1Wih = (const float*)d_in[7];
  const float* e1Whh = (const float*)d_in[8];
  const float* e1b = (const float*)d_in[9];
  const float* muW = (const float*)d_in[10];
  const float* mub = (const float*)d_in[11];
  const float* lvW = (const float*)d_in[12];
  const float* lvb = (const float*)d_in[13];
  const float* dhW = (const float*)d_in[14];
  const float* dhb = (const float*)d_in[15];
  const float* dec_emb = (const float*)d_in[16];
  const float* d0Wih = (const float*)d_in[17];
  const float* d0Whh = (const float*)d_in[18];
  const float* d0b = (const float*)d_in[19];
  const float* d1Wih = (const float*)d_in[20];
  const float* d1Whh = (const float*)d_in[21];
  const float* d1b = (const float*)d_in[22];
  const float* predW = (const float*)d_in[23];
  const float* predb = (const float*)d_in[24];
  float* out = (float*)d_out;
  (void)in_sizes; (void)n_in; (void)out_size; (void)ws_size;

  char* w = (char*)d_ws;
  size_t off = 0;
  auto alloc = [&](size_t bytes) -> void* {
    void* p = w + off;
    off += (bytes + 255) & ~(size_t)255;
    return p;
  };

  f16* e0WihH = (f16*)alloc(4096L * 320 * 2);
  f16* e0WihL = (f16*)alloc(4096L * 320 * 2);
  f16* e0WhhH = (f16*)alloc(4096L * 512 * 2);
  f16* e0WhhL = (f16*)alloc(4096L * 512 * 2);
  f16* e1WihH = (f16*)alloc(4096L * 1024 * 2);
  f16* e1WihL = (f16*)alloc(4096L * 1024 * 2);
  f16* e1WhhH = (f16*)alloc(4096L * 512 * 2);
  f16* e1WhhL = (f16*)alloc(4096L * 512 * 2);
  f16* d0WihH = (f16*)alloc(4096L * 320 * 2);
  f16* d0WihL = (f16*)alloc(4096L * 320 * 2);
  f16* d0WhhH = (f16*)alloc(4096L * 512 * 2);
  f16* d0WhhL = (f16*)alloc(4096L * 512 * 2);
  f16* d1WihH = (f16*)alloc(4096L * 1024 * 2);
  f16* d1WihL = (f16*)alloc(4096L * 1024 * 2);
  f16* d1WhhH = (f16*)alloc(4096L * 512 * 2);
  f16* d1WhhL = (f16*)alloc(4096L * 512 * 2);
  f16* muWH = (f16*)alloc(512L * 512 * 2);
  f16* muWL = (f16*)alloc(512L * 512 * 2);
  f16* lvWH = (f16*)alloc(512L * 512 * 2);
  f16* lvWL = (f16*)alloc(512L * 512 * 2);
  f16* dhWH = (f16*)alloc(512L * 512 * 2);
  f16* dhWL = (f16*)alloc(512L * 512 * 2);
  f16* predH = (f16*)alloc(50000L * 1024 * 2);
  f16* predL = (f16*)alloc(50000L * 1024 * 2);
  f16* embH = (f16*)alloc(12800L * 320 * 2);
  f16* embL = (f16*)alloc(12800L * 320 * 2);
  f16* o0H = (f16*)alloc(12800L * 1024 * 2);
  f16* o0L = (f16*)alloc(12800L * 1024 * 2);
  float* Gx = (float*)alloc(12800L * 4096 * 4);
  f16* hEncH = (f16*)alloc(2L * 2 * 32 * 512 * 2);
  f16* hEncL = (f16*)alloc(2L * 2 * 32 * 512 * 2);
  float* hid = (float*)alloc(128L * 512 * 4);
  float* cEnc = (float*)alloc(128L * 512 * 4);
  f16* hidH = (f16*)alloc(128L * 512 * 2);
  f16* hidL = (f16*)alloc(128L * 512 * 2);
  float* muBuf = (float*)alloc(128L * 512 * 4);
  float* lvBuf = (float*)alloc(128L * 512 * 4);
  f16* zH = (f16*)alloc(128L * 512 * 2);
  f16* zL = (f16*)alloc(128L * 512 * 2);
  float* hInit = (float*)alloc(128L * 512 * 4);
  f16* dhH = (f16*)alloc(4L * 32 * 512 * 2);
  f16* dhL = (f16*)alloc(4L * 32 * 512 * 2);
  float* cDec = (float*)alloc(4L * 32 * 512 * 4);
  f16* x0H = (f16*)alloc(32L * 320 * 2);
  f16* x0L = (f16*)alloc(32L * 320 * 2);
  f16* x1H = (f16*)alloc(32L * 1024 * 2);
  f16* x1L = (f16*)alloc(32L * 1024 * 2);
  f16* x2H = (f16*)alloc(32L * 1024 * 2);
  f16* x2L = (f16*)alloc(32L * 1024 * 2);
  float* Gd = (float*)alloc(32L * 4096 * 4);
  float* Hd = (float*)alloc(2L * 32 * 2048 * 4);
  float* logits = (float*)alloc(32L * 50000 * 4);
  int* tok = (int*)alloc(256);
  unsigned* bar = (unsigned*)alloc(256);

  auto grd = [](long total) -> unsigned {
    long g = (total + 255) / 256;
    return (unsigned)(g > 8192 ? 8192 : g);
  };
  auto splitW = [&](const float* src, f16* hi, f16* lo, long rows, int cs, int cd) {
    long total = rows * cd;
    k_split<<<grd(total), 256, 0, stream>>>(src, hi, lo, cs, cd, total);
  };

  // reset barrier counters (must happen every call / every graph replay)
  hipMemsetAsync(bar, 0, 256, stream);
  hipMemsetAsync(hEncH, 0, 2L * 2 * 32 * 512 * 2, stream);
  hipMemsetAsync(hEncL, 0, 2L * 2 * 32 * 512 * 2, stream);

  // weight splits
  splitW(e0Wih, e0WihH, e0WihL, 4096, 300, 320);
  splitW(e0Whh, e0WhhH, e0WhhL, 4096, 512, 512);
  splitW(e1Wih, e1WihH, e1WihL, 4096, 1024, 1024);
  splitW(e1Whh, e1WhhH, e1WhhL, 4096, 512, 512);
  splitW(d0Wih, d0WihH, d0WihL, 4096, 300, 320);
  splitW(d0Whh, d0WhhH, d0WhhL, 4096, 512, 512);
  splitW(d1Wih, d1WihH, d1WihL, 4096, 1024, 1024);
  splitW(d1Whh, d1WhhH, d1WhhL, 4096, 512, 512);
  splitW(muW, muWH, muWL, 512, 512, 512);
  splitW(lvW, lvWH, lvWL, 512, 512, 512);
  splitW(dhW, dhWH, dhWL, 512, 512, 512);
  splitW(predW, predH, predL, 50000, 1024, 1024);

  // encoder embedding gather
  k_gather<<<grd(12800L * 320), 256, 0, stream>>>(article, enc_emb, embH, embL, 12800L * 320);

  // layer 0: Gx0 = emb @ Wih0^T + b0  -> recurrence
  k_gemm<128><<<dim3(32, 100, 1), 256, 0, stream>>>(embH, embL, e0WihH, e0WihL, e0b, Gx,
                                                    12800, 4096, 320, 0, 0, 0);
  k_lstm<<<64, 256, 0, stream>>>(e0WhhH, e0WhhL, Gx, hEncH, hEncL, o0H, o0L, hid, cEnc,
                                 bar, 400, 0);

  // layer 1: Gx1 = o0 @ Wih1^T + b1 -> recurrence (final states only)
  k_gemm<128><<<dim3(32, 100, 1), 256, 0, stream>>>(o0H, o0L, e1WihH, e1WihL, e1b, Gx,
                                                    12800, 4096, 1024, 0, 0, 0);
  hipMemsetAsync(hEncH, 0, 2L * 2 * 32 * 512 * 2, stream);
  hipMemsetAsync(hEncL, 0, 2L * 2 * 32 * 512 * 2, stream);
  k_lstm<<<64, 256, 0, stream>>>(e1WhhH, e1WhhL, Gx, hEncH, hEncL, (f16*)nullptr,
                                 (f16*)nullptr, hid, cEnc, bar + 16, 400, 1);

  // VAE
  splitW(hid, hidH, hidL, 128, 512, 512);
  k_gemm<32><<<dim3(4, 4, 1), 256, 0, stream>>>(hidH, hidL, muWH, muWL, mub, muBuf,
                                                128, 512, 512, 0, 0, 0);
  k_gemm<32><<<dim3(4, 4, 1), 256, 0, stream>>>(hidH, hidL, lvWH, lvWL, lvb, lvBuf,
                                                128, 512, 512, 0, 0, 0);
  k_vae<<<256, 256, 0, stream>>>(muBuf, lvBuf, z_noise, out + 24000000L, out + 24065536L,
                                 out + 24131072L, zH, zL);
  k_gemm<32><<<dim3(4, 4, 1), 256, 0, stream>>>(zH, zL, dhWH, dhWL, dhb, hInit,
                                                128, 512, 512, 0, 0, 0);
  k_decinit<<<256, 256, 0, stream>>>(hInit, cEnc, summary, dhH, dhL, cDec, tok);

  // decoder greedy loop
  for (int t = 0; t < 15; ++t) {
    k_gather<<<40, 256, 0, stream>>>(tok, dec_emb, x0H, x0L, 32L * 320);
    k_gemm<32><<<dim3(32, 1, 1), 256, 0, stream>>>(x0H, x0L, d0WihH, d0WihL, d0b, Gd,
                                                   32, 4096, 320, 0, 0, 0);
    k_gemm<32><<<dim3(16, 1, 2), 256, 0, stream>>>(dhH, dhL, d0WhhH, d0WhhL,
                                                   (const float*)nullptr, Hd, 32, 2048, 512,
                                                   16384, 1048576, 65536);
    k_cell<<<128, 256, 0, stream>>>(Gd, Hd, cDec, dhH, dhL, x1H, x1L, 0);
    k_gemm<32><<<dim3(32, 1, 1), 256, 0, stream>>>(x1H, x1L, d1WihH, d1WihL, d1b, Gd,
                                                   32, 4096, 1024, 0, 0, 0);
    k_gemm<32><<<dim3(16, 1, 2), 256, 0, stream>>>(dhH + 32768, dhL + 32768, d1WhhH, d1WhhL,
                                                   (const float*)nullptr, Hd, 32, 2048, 512,
                                                   16384, 1048576, 65536);
    k_cell<<<128, 256, 0, stream>>>(Gd, Hd, cDec, dhH, dhL, x2H, x2L, 1);
    k_gemm<32><<<dim3(391, 1, 1), 256, 0, stream>>>(x2H, x2L, predH, predL, predb, logits,
                                                    32, 50000, 1024, 0, 0, 0);
    k_lsm<<<32, 256, 0, stream>>>(logits, out, tok, t);
  }
}

// Round 2
// 11123.813 us; speedup vs baseline: 1.6078x; 1.6078x over previous
//
#include <hip/hip_runtime.h>
#include <math.h>

typedef _Float16 f16;
typedef __attribute__((__ext_vector_type__(8))) _Float16 f16x8;
typedef __attribute__((__ext_vector_type__(4))) float f32x4;

static __device__ __forceinline__ f32x4 mfma16(f16x8 a, f16x8 b, f32x4 c) {
  return __builtin_amdgcn_mfma_f32_16x16x32_f16(a, b, c, 0, 0, 0);
}
static __device__ __forceinline__ float sigf(float x) { return 1.0f / (1.0f + expf(-x)); }
static __device__ __forceinline__ void split2(float v, f16* hi, f16* lo) {
  f16 h = (f16)v;
  *hi = h;
  *lo = (f16)((v - (float)h) * 2048.0f);  // scaled lo-plane: avoids f16 denormal flush
}
static __device__ __forceinline__ unsigned packh(f16 a, f16 b) {
  union { f16 f; unsigned short u; } ua, ub;
  ua.f = a; ub.f = b;
  return (unsigned)ua.u | ((unsigned)ub.u << 16);
}

// ---------------- fp32 -> f16 hi/lo planes (row padding cs->cd with zeros) ---------
__global__ void k_split(const float* __restrict__ src, f16* __restrict__ hi,
                        f16* __restrict__ lo, int cs, int cd, long total) {
  for (long i = (long)blockIdx.x * 256 + threadIdx.x; i < total; i += (long)gridDim.x * 256) {
    int r = (int)(i / cd), c = (int)(i % cd);
    float v = (c < cs) ? src[(long)r * cs + c] : 0.0f;
    split2(v, &hi[i], &lo[i]);
  }
}

// ---------------- embedding gather + split (rows of 300 padded to 320) -------------
__global__ void k_gather(const int* __restrict__ idx, const float* __restrict__ tab,
                         f16* __restrict__ hi, f16* __restrict__ lo, long total) {
  for (long i = (long)blockIdx.x * 256 + threadIdx.x; i < total; i += (long)gridDim.x * 256) {
    int r = (int)(i / 320), c = (int)(i % 320);
    float v = (c < 300) ? tab[(long)idx[r] * 300 + c] : 0.0f;
    split2(v, &hi[i], &lo[i]);
  }
}

// ---------------- split-f16 GEMM: C[M,N] = A[M,K] @ B[N,K]^T (+bias) --------------
template <int BM>
__global__ __launch_bounds__(256, 1) void k_gemm(
    const f16* __restrict__ Ahi, const f16* __restrict__ Alo,
    const f16* __restrict__ Bhi, const f16* __restrict__ Blo,
    const float* __restrict__ bias, float* __restrict__ C,
    int M, int N, int K, long aB, long bB, long cB) {
  constexpr int MF = (BM == 128) ? 4 : 2;
  constexpr int NF = (BM == 128) ? 4 : 2;
  __shared__ f16 sA[2][BM][72];
  __shared__ f16 sB[2][128][72];

  const int tid = threadIdx.x;
  const int wid = tid >> 6, lane = tid & 63;
  const int ln = lane & 15, l4 = lane >> 4;
  const int m0 = blockIdx.y * BM;
  const int n0 = blockIdx.x * 128;
  const int z = blockIdx.z;
  const f16* pAh = Ahi + (long)z * aB;
  const f16* pAl = Alo + (long)z * aB;
  const f16* pBh = Bhi + (long)z * bB;
  const f16* pBl = Blo + (long)z * bB;
  float* pC = C + (long)z * cB;

  const int wrow = (BM == 128) ? (wid >> 1) * 64 : 0;
  const int wcol = (BM == 128) ? (wid & 1) * 64 : wid * 32;

  f32x4 am[MF][NF], ax[MF][NF];
#pragma unroll
  for (int i = 0; i < MF; ++i)
#pragma unroll
    for (int j = 0; j < NF; ++j) {
      am[i][j] = (f32x4){0.f, 0.f, 0.f, 0.f};
      ax[i][j] = (f32x4){0.f, 0.f, 0.f, 0.f};
    }

  for (int k0 = 0; k0 < K; k0 += 64) {
#pragma unroll
    for (int p = 0; p < 2; ++p) {
      const f16* sa = p ? pAl : pAh;
      for (int i = tid; i < BM * 8; i += 256) {
        int r = i >> 3, ch = i & 7;
        uint4 v = make_uint4(0u, 0u, 0u, 0u);
        int gr = m0 + r;
        if (gr < M) v = *(const uint4*)(sa + (long)gr * K + k0 + ch * 8);
        *(uint4*)&sA[p][r][ch * 8] = v;
      }
      const f16* sb = p ? pBl : pBh;
      for (int i = tid; i < 1024; i += 256) {
        int r = i >> 3, ch = i & 7;
        uint4 v = make_uint4(0u, 0u, 0u, 0u);
        int gn = n0 + r;
        if (gn < N) v = *(const uint4*)(sb + (long)gn * K + k0 + ch * 8);
        *(uint4*)&sB[p][r][ch * 8] = v;
      }
    }
    __syncthreads();
#pragma unroll
    for (int kk = 0; kk < 64; kk += 32) {
      const int kc = kk + l4 * 8;
      f16x8 ah[MF], al[MF], bh[NF], bl[NF];
#pragma unroll
      for (int i = 0; i < MF; ++i) {
        ah[i] = *(const f16x8*)&sA[0][wrow + i * 16 + ln][kc];
        al[i] = *(const f16x8*)&sA[1][wrow + i * 16 + ln][kc];
      }
#pragma unroll
      for (int j = 0; j < NF; ++j) {
        bh[j] = *(const f16x8*)&sB[0][wcol + j * 16 + ln][kc];
        bl[j] = *(const f16x8*)&sB[1][wcol + j * 16 + ln][kc];
      }
#pragma unroll
      for (int i = 0; i < MF; ++i)
#pragma unroll
        for (int j = 0; j < NF; ++j) {
          am[i][j] = mfma16(ah[i], bh[j], am[i][j]);
          ax[i][j] = mfma16(ah[i], bl[j], ax[i][j]);
          ax[i][j] = mfma16(al[i], bh[j], ax[i][j]);
        }
    }
    __syncthreads();
  }
#pragma unroll
  for (int i = 0; i < MF; ++i)
#pragma unroll
    for (int j = 0; j < NF; ++j) {
      int row = m0 + wrow + i * 16 + l4 * 4;
      int col = n0 + wcol + j * 16 + ln;
      if (col < N) {
        float bv = bias ? bias[col] : 0.0f;
#pragma unroll
        for (int r = 0; r < 4; ++r)
          if (row + r < M)
            pC[(long)(row + r) * N + col] = am[i][j][r] + ax[i][j][r] * (1.0f / 2048.0f) + bv;
      }
    }
}

// ---------------- persistent bidirectional LSTM layer (v2: coherent-bypass sync) ----
// 64 WGs (2 dirs x 32), 1 WG/CU. Whh slice lives in REGISTERS (32 f16x8/lane).
// h exchanged via sc0sc1 (L1/L2-bypass, LLC-coherent) loads/stores; barrier is
// relaxed-atomic only -> NO buffer_inv / buffer_wbl2 anywhere in the loop.
__global__ __launch_bounds__(256, 1) void k_lstm(
    const f16* __restrict__ WhhHi, const f16* __restrict__ WhhLo,  // [2*2048][512]
    const float* __restrict__ Gx,                                  // [S*32][4096]
    f16* __restrict__ hHi, f16* __restrict__ hLo,                  // [2par][2dir][32][512]
    f16* __restrict__ oHi, f16* __restrict__ oLo,                  // [S*32][1024] or null
    float* __restrict__ hidOut, float* __restrict__ cOut,          // [4][32][512]
    unsigned* __restrict__ bar, int S, int layer) {
  const int tid = threadIdx.x;
  const int d = blockIdx.x >> 5;
  const int wg = blockIdx.x & 31;
  const int j0 = wg * 16;

  __shared__ f16 sHh[32][520];
  __shared__ f16 sHl[32][520];
  __shared__ float sGate[2][4][32][16];

  const int wid = tid >> 6, lane = tid & 63;
  const int gh = wid & 1, kh = wid >> 1;
  const int ln = lane & 15, lk8 = (lane >> 4) * 8;

  // persistent Whh fragments in registers (gates gh*2..gh*2+1, k-half kh)
  f16x8 wbh[2][8], wbl[2][8];
#pragma unroll
  for (int gl = 0; gl < 2; ++gl) {
    const long rowb = ((long)d * 2048 + (gh * 2 + gl) * 512 + j0 + ln) << 9;
#pragma unroll
    for (int ks = 0; ks < 8; ++ks) {
      const long off = rowb + (kh * 8 + ks) * 32 + lk8;
      wbh[gl][ks] = *(const f16x8*)(WhhHi + off);
      wbl[gl][ks] = *(const f16x8*)(WhhLo + off);
    }
  }

  unsigned* myBar = bar + d * 64;
  const int cb = tid >> 3;       // cell phase: batch row
  const int cj = (tid & 7) * 2;  // cell phase: col pair within owned 16
  float creg0 = 0.0f, creg1 = 0.0f;
  unsigned calls = 0;

  for (int t = 0; t < S; ++t) {
    const int trow = d ? (S - 1 - t) : t;
    const int par = t & 1;

    // prefetch Gx for the cell phase (normal cached loads; hidden under staging+GEMM)
    float2 gxv[4];
#pragma unroll
    for (int g = 0; g < 4; ++g)
      gxv[g] = *(const float2*)&Gx[((long)trow * 32 + cb) * 4096 + (long)d * 2048 + g * 512 + j0 + cj];

    // stage h(t-1) for this dir into LDS via coherence-point loads (sc0 sc1)
    {
      const char* hb = (const char*)(hHi + ((long)par * 2 + d) * 32 * 512);
      const char* lb = (const char*)(hLo + ((long)par * 2 + d) * 32 * 512);
      uint4 hv[16];
#pragma unroll
      for (int q = 0; q < 8; ++q) {
        const char* p = hb + (((long)q * 256 + tid) << 4);
        asm volatile("global_load_dwordx4 %0, %1, off sc0 sc1" : "=v"(hv[q]) : "v"(p));
      }
#pragma unroll
      for (int q = 0; q < 8; ++q) {
        const char* p = lb + (((long)q * 256 + tid) << 4);
        asm volatile("global_load_dwordx4 %0, %1, off sc0 sc1" : "=v"(hv[8 + q]) : "v"(p));
      }
      asm volatile("s_waitcnt vmcnt(0)" ::: "memory");
#pragma unroll
      for (int q = 0; q < 8; ++q) {
        int c = q * 256 + tid;
        *(uint4*)&sHh[c >> 6][(c & 63) * 8] = hv[q];
        *(uint4*)&sHl[c >> 6][(c & 63) * 8] = hv[8 + q];
      }
    }
    __syncthreads();

    // recurrent GEMM: A = h (LDS), B = Whh fragments (registers)
    f32x4 am[2][2], ax[2][2];
#pragma unroll
    for (int a = 0; a < 2; ++a)
#pragma unroll
      for (int b2 = 0; b2 < 2; ++b2) {
        am[a][b2] = (f32x4){0.f, 0.f, 0.f, 0.f};
        ax[a][b2] = (f32x4){0.f, 0.f, 0.f, 0.f};
      }
#pragma unroll
    for (int ks = 0; ks < 8; ++ks) {
      const int kc = (kh * 8 + ks) * 32 + lk8;
      f16x8 a0h = *(const f16x8*)&sHh[ln][kc];
      f16x8 a1h = *(const f16x8*)&sHh[16 + ln][kc];
      f16x8 a0l = *(const f16x8*)&sHl[ln][kc];
      f16x8 a1l = *(const f16x8*)&sHl[16 + ln][kc];
#pragma unroll
      for (int gl = 0; gl < 2; ++gl) {
        am[gl][0] = mfma16(a0h, wbh[gl][ks], am[gl][0]);
        ax[gl][0] = mfma16(a0h, wbl[gl][ks], ax[gl][0]);
        ax[gl][0] = mfma16(a0l, wbh[gl][ks], ax[gl][0]);
        am[gl][1] = mfma16(a1h, wbh[gl][ks], am[gl][1]);
        ax[gl][1] = mfma16(a1h, wbl[gl][ks], ax[gl][1]);
        ax[gl][1] = mfma16(a1l, wbh[gl][ks], ax[gl][1]);
      }
    }

    // deposit partial gates
#pragma unroll
    for (int gl = 0; gl < 2; ++gl) {
      const int g = gh * 2 + gl;
#pragma unroll
      for (int mf = 0; mf < 2; ++mf) {
        const int row = mf * 16 + (lane >> 4) * 4;
#pragma unroll
        for (int r = 0; r < 4; ++r)
          sGate[kh][g][row + r][ln] = am[gl][mf][r] + ax[gl][mf][r] * (1.0f / 2048.0f);
      }
    }
    __syncthreads();

    // cell update: thread owns (cb, cols cj, cj+1); c-state stays in registers
    {
      float i0 = sGate[0][0][cb][cj] + sGate[1][0][cb][cj] + gxv[0].x;
      float i1 = sGate[0][0][cb][cj + 1] + sGate[1][0][cb][cj + 1] + gxv[0].y;
      float f0 = sGate[0][1][cb][cj] + sGate[1][1][cb][cj] + gxv[1].x;
      float f1 = sGate[0][1][cb][cj + 1] + sGate[1][1][cb][cj + 1] + gxv[1].y;
      float g0 = sGate[0][2][cb][cj] + sGate[1][2][cb][cj] + gxv[2].x;
      float g1 = sGate[0][2][cb][cj + 1] + sGate[1][2][cb][cj + 1] + gxv[2].y;
      float o0 = sGate[0][3][cb][cj] + sGate[1][3][cb][cj] + gxv[3].x;
      float o1 = sGate[0][3][cb][cj + 1] + sGate[1][3][cb][cj + 1] + gxv[3].y;
      float c0 = sigf(f0) * creg0 + sigf(i0) * tanhf(g0);
      float c1 = sigf(f1) * creg1 + sigf(i1) * tanhf(g1);
      creg0 = c0; creg1 = c1;
      float h0 = sigf(o0) * tanhf(c0);
      float h1 = sigf(o1) * tanhf(c1);
      f16 h0h, h0l, h1h, h1l;
      split2(h0, &h0h, &h0l);
      split2(h1, &h1h, &h1l);
      unsigned phi = packh(h0h, h1h), plo = packh(h0l, h1l);
      long ho = ((((long)(par ^ 1) * 2 + d) * 32 + cb) * 512 + j0 + cj);
      char* dh = (char*)(hHi + ho);
      char* dl = (char*)(hLo + ho);
      asm volatile("global_store_dword %0, %1, off sc0 sc1" ::"v"(dh), "v"(phi) : "memory");
      asm volatile("global_store_dword %0, %1, off sc0 sc1" ::"v"(dl), "v"(plo) : "memory");
      if (oHi) {
        long oo = ((long)trow * 32 + cb) * 1024 + (long)d * 512 + j0 + cj;
        *(unsigned*)(oHi + oo) = phi;
        *(unsigned*)(oLo + oo) = plo;
      }
      if (t == S - 1) {
        long so = (((long)layer * 2 + d) * 32 + cb) * 512 + j0 + cj;
        *(float2*)(hidOut + so) = make_float2(h0, h1);
        *(float2*)(cOut + so) = make_float2(c0, c1);
      }
    }

    // barrier: relaxed atomics only (h stores already acked at coherence point)
    asm volatile("s_waitcnt vmcnt(0)" ::: "memory");
    __syncthreads();
    if (tid == 0) {
      __hip_atomic_fetch_add(myBar, 1u, __ATOMIC_RELAXED, __HIP_MEMORY_SCOPE_AGENT);
      ++calls;
      unsigned tgt = calls * 32u;
      while (__hip_atomic_load(myBar, __ATOMIC_RELAXED, __HIP_MEMORY_SCOPE_AGENT) < tgt)
        __builtin_amdgcn_s_sleep(1);
    }
    __syncthreads();
  }
}

// ---------------- VAE elementwise ---------------------------------------------------
__global__ void k_vae(const float* __restrict__ mu, const float* __restrict__ lv,
                      const float* __restrict__ zn, float* __restrict__ outMu,
                      float* __restrict__ outLv, float* __restrict__ outZ,
                      f16* __restrict__ zHi, f16* __restrict__ zLo) {
  int i = blockIdx.x * 256 + threadIdx.x;
  if (i >= 4 * 32 * 512) return;
  int bj = i & (32 * 512 - 1);
  float m = mu[i], l = lv[i];
  float z = zn[bj] * expf(0.5f * l) + m;
  outMu[i] = m;
  outLv[i] = l;
  outZ[i] = z;
  split2(z, &zHi[i], &zLo[i]);
}

// ---------------- decoder init ------------------------------------------------------
__global__ void k_decinit(const float* __restrict__ hInit, const float* __restrict__ cEnc,
                          const int* __restrict__ summary, f16* __restrict__ dhHi,
                          f16* __restrict__ dhLo, float* __restrict__ cDec,
                          int* __restrict__ tok) {
  int i = blockIdx.x * 256 + threadIdx.x;
  if (i < 4 * 32 * 512) {
    split2(hInit[i], &dhHi[i], &dhLo[i]);
    cDec[i] = cEnc[i];
  }
  if (i < 32) tok[i] = summary[i];  // summary[0][b]
}

// ---------------- decoder LSTM cell elementwise -------------------------------------
__global__ void k_cell(const float* __restrict__ Gd, const float* __restrict__ Hd,
                       float* __restrict__ cDec, f16* __restrict__ dhHi,
                       f16* __restrict__ dhLo, f16* __restrict__ xHi,
                       f16* __restrict__ xLo, int layer) {
  int i = blockIdx.x * 256 + threadIdx.x;
  if (i >= 2 * 32 * 512) return;
  int d = i >> 14, b = (i >> 9) & 31, j = i & 511;
  long gb = (long)b * 4096 + d * 2048 + j;
  long hb = ((long)d * 32 + b) * 2048 + j;
  float iv = Gd[gb] + Hd[hb];
  float fv = Gd[gb + 512] + Hd[hb + 512];
  float gv = Gd[gb + 1024] + Hd[hb + 1024];
  float ov = Gd[gb + 1536] + Hd[hb + 1536];
  long so = (((long)layer * 2 + d) * 32 + b) * 512 + j;
  float c_ = sigf(fv) * cDec[so] + sigf(iv) * tanhf(gv);
  cDec[so] = c_;
  float h_ = sigf(ov) * tanhf(c_);
  f16 hh, hl;
  split2(h_, &hh, &hl);
  dhHi[so] = hh;
  dhLo[so] = hl;
  long xo = (long)b * 1024 + d * 512 + j;
  xHi[xo] = hh;
  xLo[xo] = hl;
}

// ---------------- fused log-softmax + argmax (one WG per batch row) -----------------
__global__ __launch_bounds__(256) void k_lsm(const float* __restrict__ logits,
                                             float* __restrict__ outs,
                                             int* __restrict__ tok, int t) {
  const int b = blockIdx.x;
  const int tid = threadIdx.x;
  const float* lg = logits + (long)b * 50000;
  float m = -INFINITY, s = 0.0f;
  int am = 0;
  for (int v = tid; v < 50000; v += 256) {
    float x = lg[v];
    if (x > m) {
      s = s * expf(m - x) + 1.0f;
      m = x;
      am = v;
    } else {
      s += expf(x - m);
    }
  }
  __shared__ float sm[256], ss[256];
  __shared__ int sa[256];
  sm[tid] = m; ss[tid] = s; sa[tid] = am;
  __syncthreads();
  for (int o = 128; o > 0; o >>= 1) {
    if (tid < o) {
      float m2 = sm[tid + o], s2 = ss[tid + o];
      int a2 = sa[tid + o];
      float m1 = sm[tid], s1 = ss[tid];
      int a1 = sa[tid];
      if (m2 > m1 || (m2 == m1 && a2 < a1)) {
        sm[tid] = m2; ss[tid] = s2 + s1 * expf(m1 - m2); sa[tid] = a2;
      } else {
        ss[tid] = s1 + s2 * expf(m2 - m1);
      }
    }
    __syncthreads();
  }
  float lse = sm[0] + logf(ss[0]);
  float* ob = outs + ((long)t * 32 + b) * 50000;
  for (int v = tid; v < 50000; v += 256) ob[v] = lg[v] - lse;
  if (tid == 0) tok[b] = sa[0];
}

// ====================================================================================
extern "C" void kernel_launch(void* const* d_in, const int* in_sizes, int n_in,
                              void* d_out, int out_size, void* d_ws, size_t ws_size,
                              hipStream_t stream) {
  const int* article = (const int*)d_in[0];
  const int* summary = (const int*)d_in[1];
  const float* z_noise = (const float*)d_in[2];
  const float* enc_emb = (const float*)d_in[3];
  const float* e0Wih = (const float*)d_in[4];
  const float* e0Whh = (const float*)d_in[5];
  const float* e0b = (const float*)d_in[6];
  const float* e1Wih = (const float*)d_in[7];
  const float* e1Whh = (const float*)d_in[8];
  const float* e1b = (const float*)d_in[9];
  const float* muW = (const float*)d_in[10];
  const float* mub = (const float*)d_in[11];
  const float* lvW = (const float*)d_in[12];
  const float* lvb = (const float*)d_in[13];
  const float* dhW = (const float*)d_in[14];
  const float* dhb = (const float*)d_in[15];
  const float* dec_emb = (const float*)d_in[16];
  const float* d0Wih = (const float*)d_in[17];
  const float* d0Whh = (const float*)d_in[18];
  const float* d0b = (const float*)d_in[19];
  const float* d1Wih = (const float*)d_in[20];
  const float* d1Whh = (const float*)d_in[21];
  const float* d1b = (const float*)d_in[22];
  const float* predW = (const float*)d_in[23];
  const float* predb = (const float*)d_in[24];
  float* out = (float*)d_out;
  (void)in_sizes; (void)n_in; (void)out_size; (void)ws_size;

  char* w = (char*)d_ws;
  size_t off = 0;
  auto alloc = [&](size_t bytes) -> void* {
    void* p = w + off;
    off += (bytes + 255) & ~(size_t)255;
    return p;
  };

  f16* e0WihH = (f16*)alloc(4096L * 320 * 2);
  f16* e0WihL = (f16*)alloc(4096L * 320 * 2);
  f16* e0WhhH = (f16*)alloc(4096L * 512 * 2);
  f16* e0WhhL = (f16*)alloc(4096L * 512 * 2);
  f16* e1WihH = (f16*)alloc(4096L * 1024 * 2);
  f16* e1WihL = (f16*)alloc(4096L * 1024 * 2);
  f16* e1WhhH = (f16*)alloc(4096L * 512 * 2);
  f16* e1WhhL = (f16*)alloc(4096L * 512 * 2);
  f16* d0WihH = (f16*)alloc(4096L * 320 * 2);
  f16* d0WihL = (f16*)alloc(4096L * 320 * 2);
  f16* d0WhhH = (f16*)alloc(4096L * 512 * 2);
  f16* d0WhhL = (f16*)alloc(4096L * 512 * 2);
  f16* d1WihH = (f16*)alloc(4096L * 1024 * 2);
  f16* d1WihL = (f16*)alloc(4096L * 1024 * 2);
  f16* d1WhhH = (f16*)alloc(4096L * 512 * 2);
  f16* d1WhhL = (f16*)alloc(4096L * 512 * 2);
  f16* muWH = (f16*)alloc(512L * 512 * 2);
  f16* muWL = (f16*)alloc(512L * 512 * 2);
  f16* lvWH = (f16*)alloc(512L * 512 * 2);
  f16* lvWL = (f16*)alloc(512L * 512 * 2);
  f16* dhWH = (f16*)alloc(512L * 512 * 2);
  f16* dhWL = (f16*)alloc(512L * 512 * 2);
  f16* predH = (f16*)alloc(50000L * 1024 * 2);
  f16* predL = (f16*)alloc(50000L * 1024 * 2);
  f16* embH = (f16*)alloc(12800L * 320 * 2);
  f16* embL = (f16*)alloc(12800L * 320 * 2);
  f16* o0H = (f16*)alloc(12800L * 1024 * 2);
  f16* o0L = (f16*)alloc(12800L * 1024 * 2);
  float* Gx = (float*)alloc(12800L * 4096 * 4);
  f16* hEncH = (f16*)alloc(2L * 2 * 32 * 512 * 2);
  f16* hEncL = (f16*)alloc(2L * 2 * 32 * 512 * 2);
  float* hid = (float*)alloc(128L * 512 * 4);
  float* cEnc = (float*)alloc(128L * 512 * 4);
  f16* hidH = (f16*)alloc(128L * 512 * 2);
  f16* hidL = (f16*)alloc(128L * 512 * 2);
  float* muBuf = (float*)alloc(128L * 512 * 4);
  float* lvBuf = (float*)alloc(128L * 512 * 4);
  f16* zH = (f16*)alloc(128L * 512 * 2);
  f16* zL = (f16*)alloc(128L * 512 * 2);
  float* hInit = (float*)alloc(128L * 512 * 4);
  f16* dhH = (f16*)alloc(4L * 32 * 512 * 2);
  f16* dhL = (f16*)alloc(4L * 32 * 512 * 2);
  float* cDec = (float*)alloc(4L * 32 * 512 * 4);
  f16* x0H = (f16*)alloc(32L * 320 * 2);
  f16* x0L = (f16*)alloc(32L * 320 * 2);
  f16* x1H = (f16*)alloc(32L * 1024 * 2);
  f16* x1L = (f16*)alloc(32L * 1024 * 2);
  f16* x2H = (f16*)alloc(32L * 1024 * 2);
  f16* x2L = (f16*)alloc(32L * 1024 * 2);
  float* Gd = (float*)alloc(32L * 4096 * 4);
  float* Hd = (float*)alloc(2L * 32 * 2048 * 4);
  float* logits = (float*)alloc(32L * 50000 * 4);
  int* tok = (int*)alloc(256);
  unsigned* bar = (unsigned*)alloc(1024);

  auto grd = [](long total) -> unsigned {
    long g = (total + 255) / 256;
    return (unsigned)(g > 8192 ? 8192 : g);
  };
  auto splitW = [&](const float* src, f16* hi, f16* lo, long rows, int cs, int cd) {
    long total = rows * cd;
    k_split<<<grd(total), 256, 0, stream>>>(src, hi, lo, cs, cd, total);
  };

  // reset barrier counters + zero h ping-pong planes (every call / graph replay)
  hipMemsetAsync(bar, 0, 1024, stream);
  hipMemsetAsync(hEncH, 0, 2L * 2 * 32 * 512 * 2, stream);
  hipMemsetAsync(hEncL, 0, 2L * 2 * 32 * 512 * 2, stream);

  // weight splits
  splitW(e0Wih, e0WihH, e0WihL, 4096, 300, 320);
  splitW(e0Whh, e0WhhH, e0WhhL, 4096, 512, 512);
  splitW(e1Wih, e1WihH, e1WihL, 4096, 1024, 1024);
  splitW(e1Whh, e1WhhH, e1WhhL, 4096, 512, 512);
  splitW(d0Wih, d0WihH, d0WihL, 4096, 300, 320);
  splitW(d0Whh, d0WhhH, d0WhhL, 4096, 512, 512);
  splitW(d1Wih, d1WihH, d1WihL, 4096, 1024, 1024);
  splitW(d1Whh, d1WhhH, d1WhhL, 4096, 512, 512);
  splitW(muW, muWH, muWL, 512, 512, 512);
  splitW(lvW, lvWH, lvWL, 512, 512, 512);
  splitW(dhW, dhWH, dhWL, 512, 512, 512);
  splitW(predW, predH, predL, 50000, 1024, 1024);

  // encoder embedding gather
  k_gather<<<grd(12800L * 320), 256, 0, stream>>>(article, enc_emb, embH, embL, 12800L * 320);

  // layer 0: Gx0 = emb @ Wih0^T + b0  -> recurrence
  k_gemm<128><<<dim3(32, 100, 1), 256, 0, stream>>>(embH, embL, e0WihH, e0WihL, e0b, Gx,
                                                    12800, 4096, 320, 0, 0, 0);
  k_lstm<<<64, 256, 0, stream>>>(e0WhhH, e0WhhL, Gx, hEncH, hEncL, o0H, o0L, hid, cEnc,
                                 bar, 400, 0);

  // layer 1: Gx1 = o0 @ Wih1^T + b1 -> recurrence (final states only)
  k_gemm<128><<<dim3(32, 100, 1), 256, 0, stream>>>(o0H, o0L, e1WihH, e1WihL, e1b, Gx,
                                                    12800, 4096, 1024, 0, 0, 0);
  hipMemsetAsync(hEncH, 0, 2L * 2 * 32 * 512 * 2, stream);
  hipMemsetAsync(hEncL, 0, 2L * 2 * 32 * 512 * 2, stream);
  k_lstm<<<64, 256, 0, stream>>>(e1WhhH, e1WhhL, Gx, hEncH, hEncL, (f16*)nullptr,
                                 (f16*)nullptr, hid, cEnc, bar + 128, 400, 1);

  // VAE
  splitW(hid, hidH, hidL, 128, 512, 512);
  k_gemm<32><<<dim3(4, 4, 1), 256, 0, stream>>>(hidH, hidL, muWH, muWL, mub, muBuf,
                                                128, 512, 512, 0, 0, 0);
  k_gemm<32><<<dim3(4, 4, 1), 256, 0, stream>>>(hidH, hidL, lvWH, lvWL, lvb, lvBuf,
                                                128, 512, 512, 0, 0, 0);
  k_vae<<<256, 256, 0, stream>>>(muBuf, lvBuf, z_noise, out + 24000000L, out + 24065536L,
                                 out + 24131072L, zH, zL);
  k_gemm<32><<<dim3(4, 4, 1), 256, 0, stream>>>(zH, zL, dhWH, dhWL, dhb, hInit,
                                                128, 512, 512, 0, 0, 0);
  k_decinit<<<256, 256, 0, stream>>>(hInit, cEnc, summary, dhH, dhL, cDec, tok);

  // decoder greedy loop
  for (int t = 0; t < 15; ++t) {
    k_gather<<<40, 256, 0, stream>>>(tok, dec_emb, x0H, x0L, 32L * 320);
    k_gemm<32><<<dim3(32, 1, 1), 256, 0, stream>>>(x0H, x0L, d0WihH, d0WihL, d0b, Gd,
                                                   32, 4096, 320, 0, 0, 0);
    k_gemm<32><<<dim3(16, 1, 2), 256, 0, stream>>>(dhH, dhL, d0WhhH, d0WhhL,
                                                   (const float*)nullptr, Hd, 32, 2048, 512,
                                                   16384, 1048576, 65536);
    k_cell<<<128, 256, 0, stream>>>(Gd, Hd, cDec, dhH, dhL, x1H, x1L, 0);
    k_gemm<32><<<dim3(32, 1, 1), 256, 0, stream>>>(x1H, x1L, d1WihH, d1WihL, d1b, Gd,
                                                   32, 4096, 1024, 0, 0, 0);
    k_gemm<32><<<dim3(16, 1, 2), 256, 0, stream>>>(dhH + 32768, dhL + 32768, d1WhhH, d1WhhL,
                                                   (const float*)nullptr, Hd, 32, 2048, 512,
                                                   16384, 1048576, 65536);
    k_cell<<<128, 256, 0, stream>>>(Gd, Hd, cDec, dhH, dhL, x2H, x2L, 1);
    k_gemm<32><<<dim3(391, 1, 1), 256, 0, stream>>>(x2H, x2L, predH, predL, predb, logits,
                                                    32, 50000, 1024, 0, 0, 0);
    k_lsm<<<32, 256, 0, stream>>>(logits, out, tok, t);
  }
}

// Round 3
// 9888.783 us; speedup vs baseline: 1.8087x; 1.1249x over previous
//
#include <hip/hip_runtime.h>
#include <math.h>

typedef _Float16 f16;
typedef __attribute__((__ext_vector_type__(8))) _Float16 f16x8;
typedef __attribute__((__ext_vector_type__(4))) float f32x4;

static __device__ __forceinline__ f32x4 mfma16(f16x8 a, f16x8 b, f32x4 c) {
  return __builtin_amdgcn_mfma_f32_16x16x32_f16(a, b, c, 0, 0, 0);
}
static __device__ __forceinline__ float sigf(float x) { return 1.0f / (1.0f + expf(-x)); }
static __device__ __forceinline__ void split2(float v, f16* hi, f16* lo) {
  f16 h = (f16)v;
  *hi = h;
  *lo = (f16)((v - (float)h) * 2048.0f);  // scaled lo-plane: avoids f16 denormal flush
}
static __device__ __forceinline__ unsigned packh(f16 a, f16 b) {
  union { f16 f; unsigned short u; } ua, ub;
  ua.f = a; ub.f = b;
  return (unsigned)ua.u | ((unsigned)ub.u << 16);
}
union H4 { f16 f[4]; uint2 u; };

// ---------------- one-shot prep: all weight splits + enc gather + bar reset --------
struct Seg {
  const float* src; const int* idx; f16* hi; f16* lo;
  long end;  // cumulative end (elements)
  int cs, cd;
};
struct SegTab { Seg s[13]; };

__global__ void k_prep(SegTab tab, long total, unsigned* bar) {
  if (blockIdx.x == 0 && threadIdx.x < 256) bar[threadIdx.x] = 0;
  for (long pos = (long)blockIdx.x * 256 + threadIdx.x; pos < total;
       pos += (long)gridDim.x * 256) {
    long start = 0; int si = 0;
    while (pos >= tab.s[si].end) { start = tab.s[si].end; ++si; }
    const Seg g = tab.s[si];
    long local = pos - start;
    float v;
    if (g.cd == 320) {
      unsigned l32 = (unsigned)local;
      unsigned r = l32 / 320u, c = l32 - r * 320u;
      long row = g.idx ? (long)g.idx[r] : (long)r;
      v = (c < 300u) ? g.src[row * 300 + c] : 0.0f;
    } else {
      v = g.src[local];
    }
    split2(v, &g.hi[local], &g.lo[local]);
  }
}

// ---------------- split-f16 GEMM: C[M,N] = A[M,K] @ B[N,K]^T (+bias) --------------
template <int BM>
__global__ __launch_bounds__(256, 1) void k_gemm(
    const f16* __restrict__ Ahi, const f16* __restrict__ Alo,
    const f16* __restrict__ Bhi, const f16* __restrict__ Blo,
    const float* __restrict__ bias, float* __restrict__ C,
    int M, int N, int K, long aB, long bB, long cB) {
  constexpr int MF = (BM == 128) ? 4 : 2;
  constexpr int NF = (BM == 128) ? 4 : 2;
  __shared__ f16 sA[2][BM][72];
  __shared__ f16 sB[2][128][72];

  const int tid = threadIdx.x;
  const int wid = tid >> 6, lane = tid & 63;
  const int ln = lane & 15, l4 = lane >> 4;
  const int m0 = blockIdx.y * BM;
  const int n0 = blockIdx.x * 128;
  const int z = blockIdx.z;
  const f16* pAh = Ahi + (long)z * aB;
  const f16* pAl = Alo + (long)z * aB;
  const f16* pBh = Bhi + (long)z * bB;
  const f16* pBl = Blo + (long)z * bB;
  float* pC = C + (long)z * cB;

  const int wrow = (BM == 128) ? (wid >> 1) * 64 : 0;
  const int wcol = (BM == 128) ? (wid & 1) * 64 : wid * 32;

  f32x4 am[MF][NF], ax[MF][NF];
#pragma unroll
  for (int i = 0; i < MF; ++i)
#pragma unroll
    for (int j = 0; j < NF; ++j) {
      am[i][j] = (f32x4){0.f, 0.f, 0.f, 0.f};
      ax[i][j] = (f32x4){0.f, 0.f, 0.f, 0.f};
    }

  for (int k0 = 0; k0 < K; k0 += 64) {
#pragma unroll
    for (int p = 0; p < 2; ++p) {
      const f16* sa = p ? pAl : pAh;
      for (int i = tid; i < BM * 8; i += 256) {
        int r = i >> 3, ch = i & 7;
        uint4 v = make_uint4(0u, 0u, 0u, 0u);
        int gr = m0 + r;
        if (gr < M) v = *(const uint4*)(sa + (long)gr * K + k0 + ch * 8);
        *(uint4*)&sA[p][r][ch * 8] = v;
      }
      const f16* sb = p ? pBl : pBh;
      for (int i = tid; i < 1024; i += 256) {
        int r = i >> 3, ch = i & 7;
        uint4 v = make_uint4(0u, 0u, 0u, 0u);
        int gn = n0 + r;
        if (gn < N) v = *(const uint4*)(sb + (long)gn * K + k0 + ch * 8);
        *(uint4*)&sB[p][r][ch * 8] = v;
      }
    }
    __syncthreads();
#pragma unroll
    for (int kk = 0; kk < 64; kk += 32) {
      const int kc = kk + l4 * 8;
      f16x8 ah[MF], al[MF], bh[NF], bl[NF];
#pragma unroll
      for (int i = 0; i < MF; ++i) {
        ah[i] = *(const f16x8*)&sA[0][wrow + i * 16 + ln][kc];
        al[i] = *(const f16x8*)&sA[1][wrow + i * 16 + ln][kc];
      }
#pragma unroll
      for (int j = 0; j < NF; ++j) {
        bh[j] = *(const f16x8*)&sB[0][wcol + j * 16 + ln][kc];
        bl[j] = *(const f16x8*)&sB[1][wcol + j * 16 + ln][kc];
      }
#pragma unroll
      for (int i = 0; i < MF; ++i)
#pragma unroll
        for (int j = 0; j < NF; ++j) {
          am[i][j] = mfma16(ah[i], bh[j], am[i][j]);
          ax[i][j] = mfma16(ah[i], bl[j], ax[i][j]);
          ax[i][j] = mfma16(al[i], bh[j], ax[i][j]);
        }
    }
    __syncthreads();
  }
#pragma unroll
  for (int i = 0; i < MF; ++i)
#pragma unroll
    for (int j = 0; j < NF; ++j) {
      int row = m0 + wrow + i * 16 + l4 * 4;
      int col = n0 + wcol + j * 16 + ln;
      if (col < N) {
        float bv = bias ? bias[col] : 0.0f;
#pragma unroll
        for (int r = 0; r < 4; ++r)
          if (row + r < M)
            pC[(long)(row + r) * N + col] = am[i][j][r] + ax[i][j][r] * (1.0f / 2048.0f) + bv;
      }
    }
}

// ---------------- persistent bidirectional LSTM layer (coherent-bypass sync) -------
// 64 WGs (2 dirs x 32), 1 WG/CU. Whh slice in registers. h exchanged via sc0sc1
// LLC-coherent loads/stores; relaxed-atomic barrier; in-kernel h-plane zeroing;
// epilogue also emits the f16 hi/lo split of hid for the VAE GEMMs.
__global__ __launch_bounds__(256, 1) void k_lstm(
    const f16* __restrict__ WhhHi, const f16* __restrict__ WhhLo,  // [2*2048][512]
    const float* __restrict__ Gx,                                  // [S*32][4096]
    f16* __restrict__ hHi, f16* __restrict__ hLo,                  // [2par][2dir][32][512]
    f16* __restrict__ oHi, f16* __restrict__ oLo,                  // [S*32][1024] or null
    float* __restrict__ hidOut, f16* __restrict__ hidOutH, f16* __restrict__ hidOutL,
    float* __restrict__ cOut,                                      // [4][32][512]
    unsigned* __restrict__ bar, int S, int layer) {
  const int tid = threadIdx.x;
  const int d = blockIdx.x >> 5;
  const int wg = blockIdx.x & 31;
  const int j0 = wg * 16;

  __shared__ f16 sHh[32][520];
  __shared__ f16 sHl[32][520];
  __shared__ float sGate[2][4][32][16];

  const int wid = tid >> 6, lane = tid & 63;
  const int gh = wid & 1, kh = wid >> 1;
  const int ln = lane & 15, lk8 = (lane >> 4) * 8;

  // persistent Whh fragments in registers (gates gh*2..gh*2+1, k-half kh)
  f16x8 wbh[2][8], wbl[2][8];
#pragma unroll
  for (int gl = 0; gl < 2; ++gl) {
    const long rowb = ((long)d * 2048 + (gh * 2 + gl) * 512 + j0 + ln) << 9;
#pragma unroll
    for (int ks = 0; ks < 8; ++ks) {
      const long off = rowb + (kh * 8 + ks) * 32 + lk8;
      wbh[gl][ks] = *(const f16x8*)(WhhHi + off);
      wbl[gl][ks] = *(const f16x8*)(WhhLo + off);
    }
  }

  unsigned* myBar = bar + d * 64;
  const int cb = tid >> 3;       // cell phase: batch row
  const int cj = (tid & 7) * 2;  // cell phase: col pair within owned 16
  float creg0 = 0.0f, creg1 = 0.0f;
  unsigned calls = 0;

  // zero par0 h plane (own slice) + initial barrier round
  {
    long zo = ((long)d * 32 + cb) * 512 + j0 + cj;  // par=0 plane
    unsigned zero = 0;
    char* zh = (char*)(hHi + zo);
    char* zl = (char*)(hLo + zo);
    asm volatile("global_store_dword %0, %1, off sc0 sc1" ::"v"(zh), "v"(zero) : "memory");
    asm volatile("global_store_dword %0, %1, off sc0 sc1" ::"v"(zl), "v"(zero) : "memory");
    asm volatile("s_waitcnt vmcnt(0)" ::: "memory");
    __syncthreads();
    if (tid == 0) {
      __hip_atomic_fetch_add(myBar, 1u, __ATOMIC_RELAXED, __HIP_MEMORY_SCOPE_AGENT);
      ++calls;
      while (__hip_atomic_load(myBar, __ATOMIC_RELAXED, __HIP_MEMORY_SCOPE_AGENT) < 32u)
        __builtin_amdgcn_s_sleep(1);
    }
    __syncthreads();
  }

  for (int t = 0; t < S; ++t) {
    const int trow = d ? (S - 1 - t) : t;
    const int par = t & 1;

    // prefetch Gx for the cell phase (normal cached loads)
    float2 gxv[4];
#pragma unroll
    for (int g = 0; g < 4; ++g)
      gxv[g] = *(const float2*)&Gx[((long)trow * 32 + cb) * 4096 + (long)d * 2048 + g * 512 + j0 + cj];

    // stage h(t-1) into LDS via coherence-point loads
    {
      const char* hb = (const char*)(hHi + ((long)par * 2 + d) * 32 * 512);
      const char* lb = (const char*)(hLo + ((long)par * 2 + d) * 32 * 512);
      uint4 hv[16];
#pragma unroll
      for (int q = 0; q < 8; ++q) {
        const char* p = hb + (((long)q * 256 + tid) << 4);
        asm volatile("global_load_dwordx4 %0, %1, off sc0 sc1" : "=v"(hv[q]) : "v"(p));
      }
#pragma unroll
      for (int q = 0; q < 8; ++q) {
        const char* p = lb + (((long)q * 256 + tid) << 4);
        asm volatile("global_load_dwordx4 %0, %1, off sc0 sc1" : "=v"(hv[8 + q]) : "v"(p));
      }
      asm volatile("s_waitcnt vmcnt(0)" ::: "memory");
#pragma unroll
      for (int q = 0; q < 8; ++q) {
        int c = q * 256 + tid;
        *(uint4*)&sHh[c >> 6][(c & 63) * 8] = hv[q];
        *(uint4*)&sHl[c >> 6][(c & 63) * 8] = hv[8 + q];
      }
    }
    __syncthreads();

    // recurrent GEMM: A = h (LDS), B = Whh fragments (registers)
    f32x4 am[2][2], ax[2][2];
#pragma unroll
    for (int a = 0; a < 2; ++a)
#pragma unroll
      for (int b2 = 0; b2 < 2; ++b2) {
        am[a][b2] = (f32x4){0.f, 0.f, 0.f, 0.f};
        ax[a][b2] = (f32x4){0.f, 0.f, 0.f, 0.f};
      }
#pragma unroll
    for (int ks = 0; ks < 8; ++ks) {
      const int kc = (kh * 8 + ks) * 32 + lk8;
      f16x8 a0h = *(const f16x8*)&sHh[ln][kc];
      f16x8 a1h = *(const f16x8*)&sHh[16 + ln][kc];
      f16x8 a0l = *(const f16x8*)&sHl[ln][kc];
      f16x8 a1l = *(const f16x8*)&sHl[16 + ln][kc];
#pragma unroll
      for (int gl = 0; gl < 2; ++gl) {
        am[gl][0] = mfma16(a0h, wbh[gl][ks], am[gl][0]);
        ax[gl][0] = mfma16(a0h, wbl[gl][ks], ax[gl][0]);
        ax[gl][0] = mfma16(a0l, wbh[gl][ks], ax[gl][0]);
        am[gl][1] = mfma16(a1h, wbh[gl][ks], am[gl][1]);
        ax[gl][1] = mfma16(a1h, wbl[gl][ks], ax[gl][1]);
        ax[gl][1] = mfma16(a1l, wbh[gl][ks], ax[gl][1]);
      }
    }

#pragma unroll
    for (int gl = 0; gl < 2; ++gl) {
      const int g = gh * 2 + gl;
#pragma unroll
      for (int mf = 0; mf < 2; ++mf) {
        const int row = mf * 16 + (lane >> 4) * 4;
#pragma unroll
        for (int r = 0; r < 4; ++r)
          sGate[kh][g][row + r][ln] = am[gl][mf][r] + ax[gl][mf][r] * (1.0f / 2048.0f);
      }
    }
    __syncthreads();

    // cell update
    {
      float i0 = sGate[0][0][cb][cj] + sGate[1][0][cb][cj] + gxv[0].x;
      float i1 = sGate[0][0][cb][cj + 1] + sGate[1][0][cb][cj + 1] + gxv[0].y;
      float f0 = sGate[0][1][cb][cj] + sGate[1][1][cb][cj] + gxv[1].x;
      float f1 = sGate[0][1][cb][cj + 1] + sGate[1][1][cb][cj + 1] + gxv[1].y;
      float g0 = sGate[0][2][cb][cj] + sGate[1][2][cb][cj] + gxv[2].x;
      float g1 = sGate[0][2][cb][cj + 1] + sGate[1][2][cb][cj + 1] + gxv[2].y;
      float o0 = sGate[0][3][cb][cj] + sGate[1][3][cb][cj] + gxv[3].x;
      float o1 = sGate[0][3][cb][cj + 1] + sGate[1][3][cb][cj + 1] + gxv[3].y;
      float c0 = sigf(f0) * creg0 + sigf(i0) * tanhf(g0);
      float c1 = sigf(f1) * creg1 + sigf(i1) * tanhf(g1);
      creg0 = c0; creg1 = c1;
      float h0 = sigf(o0) * tanhf(c0);
      float h1 = sigf(o1) * tanhf(c1);
      f16 h0h, h0l, h1h, h1l;
      split2(h0, &h0h, &h0l);
      split2(h1, &h1h, &h1l);
      unsigned phi = packh(h0h, h1h), plo = packh(h0l, h1l);
      long ho = ((((long)(par ^ 1) * 2 + d) * 32 + cb) * 512 + j0 + cj);
      char* dh = (char*)(hHi + ho);
      char* dl = (char*)(hLo + ho);
      asm volatile("global_store_dword %0, %1, off sc0 sc1" ::"v"(dh), "v"(phi) : "memory");
      asm volatile("global_store_dword %0, %1, off sc0 sc1" ::"v"(dl), "v"(plo) : "memory");
      if (oHi) {
        long oo = ((long)trow * 32 + cb) * 1024 + (long)d * 512 + j0 + cj;
        *(unsigned*)(oHi + oo) = phi;
        *(unsigned*)(oLo + oo) = plo;
      }
      if (t == S - 1) {
        long so = (((long)layer * 2 + d) * 32 + cb) * 512 + j0 + cj;
        *(float2*)(hidOut + so) = make_float2(h0, h1);
        *(unsigned*)(hidOutH + so) = phi;
        *(unsigned*)(hidOutL + so) = plo;
        *(float2*)(cOut + so) = make_float2(c0, c1);
      }
    }

    asm volatile("s_waitcnt vmcnt(0)" ::: "memory");
    __syncthreads();
    if (tid == 0) {
      __hip_atomic_fetch_add(myBar, 1u, __ATOMIC_RELAXED, __HIP_MEMORY_SCOPE_AGENT);
      ++calls;
      unsigned tgt = calls * 32u;
      while (__hip_atomic_load(myBar, __ATOMIC_RELAXED, __HIP_MEMORY_SCOPE_AGENT) < tgt)
        __builtin_amdgcn_s_sleep(1);
    }
    __syncthreads();
  }
}

// ---------------- fused decoder LSTM step (one layer, both dirs) -------------------
// grid = 32 blocks: d = blk>>4, j-tile jt = blk&15 (32 j-cols x 4 gates = 128 B rows).
// gates = x @ Wih^T + h @ Whh^T + b computed in one K-loop (X phase + H phase),
// then the cell update runs in-block; writes dhOut (ping-pong), cDec, x-out planes.
template <int XK, bool GATHER>
__global__ __launch_bounds__(256, 1) void k_dec(
    const int* __restrict__ tok, const float* __restrict__ emb,   // GATHER inputs
    const f16* __restrict__ xH, const f16* __restrict__ xL,       // !GATHER [32][XK]
    const f16* __restrict__ WihH, const f16* __restrict__ WihL,   // [2*2048][XK]
    const f16* __restrict__ WhhH, const f16* __restrict__ WhhL,   // [2*2048][512]
    const float* __restrict__ bias,                               // [2][2048]
    const f16* __restrict__ dhInH, const f16* __restrict__ dhInL, // [4][32][512]
    f16* __restrict__ dhOutH, f16* __restrict__ dhOutL,
    float* __restrict__ cDec,                                     // [4][32][512]
    f16* __restrict__ xoH, f16* __restrict__ xoL,                 // [32][1024]
    int layer) {
  const int tid = threadIdx.x;
  const int d = blockIdx.x >> 4;
  const int jt = blockIdx.x & 15;
  const int s = layer * 2 + d;
  __shared__ f16 sA[2][32][72];
  __shared__ f16 sB[2][128][72];
  __shared__ float sGate[4][32][32];

  const int wid = tid >> 6, lane = tid & 63;
  const int ln = lane & 15, l4 = lane >> 4;
  const int wcol = wid * 32;

  f32x4 am[2][2], ax[2][2];
#pragma unroll
  for (int i = 0; i < 2; ++i)
#pragma unroll
    for (int j = 0; j < 2; ++j) {
      am[i][j] = (f32x4){0.f, 0.f, 0.f, 0.f};
      ax[i][j] = (f32x4){0.f, 0.f, 0.f, 0.f};
    }

  const int ar = tid >> 3, ach = tid & 7;  // A-stage: row, 8-col chunk

#pragma unroll 1
  for (int k0 = 0; k0 < XK + 512; k0 += 64) {
    // ---- stage A (x for k0<XK, h afterwards) ----
    if (k0 < XK) {
      if (GATHER) {
        const float* rowp = emb + (long)tok[ar] * 300;
#pragma unroll
        for (int u = 0; u < 8; ++u) {
          int c = k0 + ach * 8 + u;
          float v = (c < 300) ? rowp[c] : 0.0f;
          split2(v, &sA[0][ar][ach * 8 + u], &sA[1][ar][ach * 8 + u]);
        }
      } else {
        *(uint4*)&sA[0][ar][ach * 8] = *(const uint4*)(xH + (long)ar * XK + k0 + ach * 8);
        *(uint4*)&sA[1][ar][ach * 8] = *(const uint4*)(xL + (long)ar * XK + k0 + ach * 8);
      }
    } else {
      const int hk = k0 - XK;
      *(uint4*)&sA[0][ar][ach * 8] =
          *(const uint4*)(dhInH + ((long)s * 32 + ar) * 512 + hk + ach * 8);
      *(uint4*)&sA[1][ar][ach * 8] =
          *(const uint4*)(dhInL + ((long)s * 32 + ar) * 512 + hk + ach * 8);
    }
    // ---- stage B (gate-interleaved rows) ----
#pragma unroll
    for (int q = 0; q < 4; ++q) {
      int i = tid + q * 256;
      int r = i >> 3, ch = i & 7;
      long srow = (long)d * 2048 + (r >> 5) * 512 + jt * 32 + (r & 31);
      if (k0 < XK) {
        *(uint4*)&sB[0][r][ch * 8] = *(const uint4*)(WihH + srow * XK + k0 + ch * 8);
        *(uint4*)&sB[1][r][ch * 8] = *(const uint4*)(WihL + srow * XK + k0 + ch * 8);
      } else {
        const int hk = k0 - XK;
        *(uint4*)&sB[0][r][ch * 8] = *(const uint4*)(WhhH + srow * 512 + hk + ch * 8);
        *(uint4*)&sB[1][r][ch * 8] = *(const uint4*)(WhhL + srow * 512 + hk + ch * 8);
      }
    }
    __syncthreads();
#pragma unroll
    for (int kk = 0; kk < 64; kk += 32) {
      const int kc = kk + l4 * 8;
      f16x8 ah[2], al[2], bh[2], bl[2];
#pragma unroll
      for (int i = 0; i < 2; ++i) {
        ah[i] = *(const f16x8*)&sA[0][i * 16 + ln][kc];
        al[i] = *(const f16x8*)&sA[1][i * 16 + ln][kc];
      }
#pragma unroll
      for (int j = 0; j < 2; ++j) {
        bh[j] = *(const f16x8*)&sB[0][wcol + j * 16 + ln][kc];
        bl[j] = *(const f16x8*)&sB[1][wcol + j * 16 + ln][kc];
      }
#pragma unroll
      for (int i = 0; i < 2; ++i)
#pragma unroll
        for (int j = 0; j < 2; ++j) {
          am[i][j] = mfma16(ah[i], bh[j], am[i][j]);
          ax[i][j] = mfma16(ah[i], bl[j], ax[i][j]);
          ax[i][j] = mfma16(al[i], bh[j], ax[i][j]);
        }
    }
    __syncthreads();
  }

  // deposit gates: warp wid holds gate wid for 32 j x 32 b
#pragma unroll
  for (int i = 0; i < 2; ++i)
#pragma unroll
    for (int jf = 0; jf < 2; ++jf)
#pragma unroll
      for (int r = 0; r < 4; ++r) {
        int b = i * 16 + l4 * 4 + r;
        int jj = jf * 16 + ln;
        sGate[wid][b][jj] = am[i][jf][r] + ax[i][jf][r] * (1.0f / 2048.0f);
      }
  __syncthreads();

  // cell update: thread owns (b, 4 consecutive j)
  {
    const int b = tid >> 3, q0 = (tid & 7) * 4;
    H4 phi, plo;
    float cv[4];
#pragma unroll
    for (int u = 0; u < 4; ++u) {
      int jj = q0 + u;
      int j = jt * 32 + jj;
      float iv = sGate[0][b][jj] + bias[d * 2048 + j];
      float fv = sGate[1][b][jj] + bias[d * 2048 + 512 + j];
      float gv = sGate[2][b][jj] + bias[d * 2048 + 1024 + j];
      float ov = sGate[3][b][jj] + bias[d * 2048 + 1536 + j];
      long co = ((long)s * 32 + b) * 512 + j;
      float c_ = sigf(fv) * cDec[co] + sigf(iv) * tanhf(gv);
      cv[u] = c_;
      float h_ = sigf(ov) * tanhf(c_);
      split2(h_, &phi.f[u], &plo.f[u]);
    }
    long base = ((long)s * 32 + b) * 512 + jt * 32 + q0;
    *(float4*)&cDec[base] = make_float4(cv[0], cv[1], cv[2], cv[3]);
    *(uint2*)&dhOutH[base] = phi.u;
    *(uint2*)&dhOutL[base] = plo.u;
    long xo = (long)b * 1024 + d * 512 + jt * 32 + q0;
    *(uint2*)&xoH[xo] = phi.u;
    *(uint2*)&xoL[xo] = plo.u;
  }
}

// ---------------- VAE elementwise (adds mu/lv biases) -------------------------------
__global__ void k_vae(const float* __restrict__ mlOut, const float* __restrict__ mub,
                      const float* __restrict__ lvb, const float* __restrict__ zn,
                      float* __restrict__ outMu, float* __restrict__ outLv,
                      float* __restrict__ outZ, f16* __restrict__ zHi,
                      f16* __restrict__ zLo) {
  int i = blockIdx.x * 256 + threadIdx.x;
  if (i >= 4 * 32 * 512) return;
  int bj = i & (32 * 512 - 1);
  int j = i & 511;
  float m = mlOut[i] + mub[j];
  float l = mlOut[65536 + i] + lvb[j];
  float z = zn[bj] * expf(0.5f * l) + m;
  outMu[i] = m;
  outLv[i] = l;
  outZ[i] = z;
  split2(z, &zHi[i], &zLo[i]);
}

// ---------------- decoder init ------------------------------------------------------
__global__ void k_decinit(const float* __restrict__ hInit, const float* __restrict__ cEnc,
                          const int* __restrict__ summary, f16* __restrict__ dhHi,
                          f16* __restrict__ dhLo, float* __restrict__ cDec,
                          int* __restrict__ tok) {
  int i = blockIdx.x * 256 + threadIdx.x;
  if (i < 4 * 32 * 512) {
    split2(hInit[i], &dhHi[i], &dhLo[i]);
    cDec[i] = cEnc[i];
  }
  if (i < 32) tok[i] = summary[i];  // summary[0][b]
}

// ---------------- fused log-softmax + argmax (one WG per batch row) -----------------
__global__ __launch_bounds__(256) void k_lsm(const float* __restrict__ logits,
                                             float* __restrict__ outs,
                                             int* __restrict__ tok, int t) {
  const int b = blockIdx.x;
  const int tid = threadIdx.x;
  const float* lg = logits + (long)b * 50000;
  float m = -INFINITY, s = 0.0f;
  int am = 0;
  for (int v = tid; v < 50000; v += 256) {
    float x = lg[v];
    if (x > m) {
      s = s * expf(m - x) + 1.0f;
      m = x;
      am = v;
    } else {
      s += expf(x - m);
    }
  }
  __shared__ float sm[256], ss[256];
  __shared__ int sa[256];
  sm[tid] = m; ss[tid] = s; sa[tid] = am;
  __syncthreads();
  for (int o = 128; o > 0; o >>= 1) {
    if (tid < o) {
      float m2 = sm[tid + o], s2 = ss[tid + o];
      int a2 = sa[tid + o];
      float m1 = sm[tid], s1 = ss[tid];
      int a1 = sa[tid];
      if (m2 > m1 || (m2 == m1 && a2 < a1)) {
        sm[tid] = m2; ss[tid] = s2 + s1 * expf(m1 - m2); sa[tid] = a2;
      } else {
        ss[tid] = s1 + s2 * expf(m2 - m1);
      }
    }
    __syncthreads();
  }
  float lse = sm[0] + logf(ss[0]);
  float* ob = outs + ((long)t * 32 + b) * 50000;
  for (int v = tid; v < 50000; v += 256) ob[v] = lg[v] - lse;
  if (tid == 0) tok[b] = sa[0];
}

// ====================================================================================
extern "C" void kernel_launch(void* const* d_in, const int* in_sizes, int n_in,
                              void* d_out, int out_size, void* d_ws, size_t ws_size,
                              hipStream_t stream) {
  const int* article = (const int*)d_in[0];
  const int* summary = (const int*)d_in[1];
  const float* z_noise = (const float*)d_in[2];
  const float* enc_emb = (const float*)d_in[3];
  const float* e0Wih = (const float*)d_in[4];
  const float* e0Whh = (const float*)d_in[5];
  const float* e0b = (const float*)d_in[6];
  const float* e1Wih = (const float*)d_in[7];
  const float* e1Whh = (const float*)d_in[8];
  const float* e1b = (const float*)d_in[9];
  const float* muW = (const float*)d_in[10];
  const float* mub = (const float*)d_in[11];
  const float* lvW = (const float*)d_in[12];
  const float* lvb = (const float*)d_in[13];
  const float* dhW = (const float*)d_in[14];
  const float* dhb = (const float*)d_in[15];
  const float* dec_emb = (const float*)d_in[16];
  const float* d0Wih = (const float*)d_in[17];
  const float* d0Whh = (const float*)d_in[18];
  const float* d0b = (const float*)d_in[19];
  const float* d1Wih = (const float*)d_in[20];
  const float* d1Whh = (const float*)d_in[21];
  const float* d1b = (const float*)d_in[22];
  const float* predW = (const float*)d_in[23];
  const float* predb = (const float*)d_in[24];
  float* out = (float*)d_out;
  (void)in_sizes; (void)n_in; (void)out_size; (void)ws_size;

  char* w = (char*)d_ws;
  size_t off = 0;
  auto alloc = [&](size_t bytes) -> void* {
    void* p = w + off;
    off += (bytes + 255) & ~(size_t)255;
    return p;
  };

  f16* e0WihH = (f16*)alloc(4096L * 320 * 2);
  f16* e0WihL = (f16*)alloc(4096L * 320 * 2);
  f16* e0WhhH = (f16*)alloc(4096L * 512 * 2);
  f16* e0WhhL = (f16*)alloc(4096L * 512 * 2);
  f16* e1WihH = (f16*)alloc(4096L * 1024 * 2);
  f16* e1WihL = (f16*)alloc(4096L * 1024 * 2);
  f16* e1WhhH = (f16*)alloc(4096L * 512 * 2);
  f16* e1WhhL = (f16*)alloc(4096L * 512 * 2);
  f16* d0WihH = (f16*)alloc(4096L * 320 * 2);
  f16* d0WihL = (f16*)alloc(4096L * 320 * 2);
  f16* d0WhhH = (f16*)alloc(4096L * 512 * 2);
  f16* d0WhhL = (f16*)alloc(4096L * 512 * 2);
  f16* d1WihH = (f16*)alloc(4096L * 1024 * 2);
  f16* d1WihL = (f16*)alloc(4096L * 1024 * 2);
  f16* d1WhhH = (f16*)alloc(4096L * 512 * 2);
  f16* d1WhhL = (f16*)alloc(4096L * 512 * 2);
  f16* mlWH = (f16*)alloc(2L * 262144 * 2);   // muW hi | lvW hi
  f16* mlWL = (f16*)alloc(2L * 262144 * 2);
  f16* dhWH = (f16*)alloc(512L * 512 * 2);
  f16* dhWL = (f16*)alloc(512L * 512 * 2);
  f16* predH = (f16*)alloc(50000L * 1024 * 2);
  f16* predL = (f16*)alloc(50000L * 1024 * 2);
  f16* embH = (f16*)alloc(12800L * 320 * 2);
  f16* embL = (f16*)alloc(12800L * 320 * 2);
  f16* o0H = (f16*)alloc(12800L * 1024 * 2);
  f16* o0L = (f16*)alloc(12800L * 1024 * 2);
  float* Gx = (float*)alloc(12800L * 4096 * 4);
  f16* hEncH = (f16*)alloc(2L * 2 * 32 * 512 * 2);
  f16* hEncL = (f16*)alloc(2L * 2 * 32 * 512 * 2);
  float* hid = (float*)alloc(128L * 512 * 4);
  float* cEnc = (float*)alloc(128L * 512 * 4);
  f16* hidH = (f16*)alloc(128L * 512 * 2);
  f16* hidL = (f16*)alloc(128L * 512 * 2);
  float* mlOut = (float*)alloc(2L * 65536 * 4);  // mu | lv (pre-bias)
  f16* zH = (f16*)alloc(128L * 512 * 2);
  f16* zL = (f16*)alloc(128L * 512 * 2);
  float* hInit = (float*)alloc(128L * 512 * 4);
  f16* dhH = (f16*)alloc(2L * 65536 * 2);  // [2 par][4][32][512]
  f16* dhL = (f16*)alloc(2L * 65536 * 2);
  float* cDec = (float*)alloc(4L * 32 * 512 * 4);
  f16* x1H = (f16*)alloc(32L * 1024 * 2);
  f16* x1L = (f16*)alloc(32L * 1024 * 2);
  f16* x2H = (f16*)alloc(32L * 1024 * 2);
  f16* x2L = (f16*)alloc(32L * 1024 * 2);
  float* logits = (float*)alloc(32L * 50000 * 4);
  int* tok = (int*)alloc(256);
  unsigned* bar = (unsigned*)alloc(1024);

  // ---- single prep kernel: all splits + enc gather + bar reset ----
  SegTab tab;
  long cum = 0;
  int si = 0;
  auto seg = [&](const float* src, const int* idx, f16* hi, f16* lo, long rows, int cs,
                 int cd) {
    cum += rows * cd;
    tab.s[si++] = Seg{src, idx, hi, lo, cum, cs, cd};
  };
  seg(e0Wih, nullptr, e0WihH, e0WihL, 4096, 300, 320);
  seg(e0Whh, nullptr, e0WhhH, e0WhhL, 4096, 512, 512);
  seg(e1Wih, nullptr, e1WihH, e1WihL, 4096, 1024, 1024);
  seg(e1Whh, nullptr, e1WhhH, e1WhhL, 4096, 512, 512);
  seg(d0Wih, nullptr, d0WihH, d0WihL, 4096, 300, 320);
  seg(d0Whh, nullptr, d0WhhH, d0WhhL, 4096, 512, 512);
  seg(d1Wih, nullptr, d1WihH, d1WihL, 4096, 1024, 1024);
  seg(d1Whh, nullptr, d1WhhH, d1WhhL, 4096, 512, 512);
  seg(muW, nullptr, mlWH, mlWL, 512, 512, 512);
  seg(lvW, nullptr, mlWH + 262144, mlWL + 262144, 512, 512, 512);
  seg(dhW, nullptr, dhWH, dhWL, 512, 512, 512);
  seg(predW, nullptr, predH, predL, 50000, 1024, 1024);
  seg(enc_emb, article, embH, embL, 12800, 300, 320);
  k_prep<<<8192, 256, 0, stream>>>(tab, cum, bar);

  // ---- encoder ----
  k_gemm<128><<<dim3(32, 100, 1), 256, 0, stream>>>(embH, embL, e0WihH, e0WihL, e0b, Gx,
                                                    12800, 4096, 320, 0, 0, 0);
  k_lstm<<<64, 256, 0, stream>>>(e0WhhH, e0WhhL, Gx, hEncH, hEncL, o0H, o0L, hid, hidH,
                                 hidL, cEnc, bar, 400, 0);
  k_gemm<128><<<dim3(32, 100, 1), 256, 0, stream>>>(o0H, o0L, e1WihH, e1WihL, e1b, Gx,
                                                    12800, 4096, 1024, 0, 0, 0);
  k_lstm<<<64, 256, 0, stream>>>(e1WhhH, e1WhhL, Gx, hEncH, hEncL, (f16*)nullptr,
                                 (f16*)nullptr, hid, hidH, hidL, cEnc, bar + 128, 400, 1);

  // ---- VAE (mu+lv batched) ----
  k_gemm<32><<<dim3(4, 4, 2), 256, 0, stream>>>(hidH, hidL, mlWH, mlWL,
                                                (const float*)nullptr, mlOut, 128, 512,
                                                512, 0, 262144, 65536);
  k_vae<<<256, 256, 0, stream>>>(mlOut, mub, lvb, z_noise, out + 24000000L,
                                 out + 24065536L, out + 24131072L, zH, zL);
  k_gemm<32><<<dim3(4, 4, 1), 256, 0, stream>>>(zH, zL, dhWH, dhWL, dhb, hInit, 128, 512,
                                                512, 0, 0, 0);
  k_decinit<<<256, 256, 0, stream>>>(hInit, cEnc, summary, dhH, dhL, cDec, tok);

  // ---- decoder greedy loop (4 nodes/step) ----
  for (int t = 0; t < 15; ++t) {
    int par = t & 1;
    f16* dIH = dhH + (long)par * 65536;
    f16* dIL = dhL + (long)par * 65536;
    f16* dOH = dhH + (long)(par ^ 1) * 65536;
    f16* dOL = dhL + (long)(par ^ 1) * 65536;
    k_dec<320, true><<<32, 256, 0, stream>>>(tok, dec_emb, (const f16*)nullptr,
                                             (const f16*)nullptr, d0WihH, d0WihL, d0WhhH,
                                             d0WhhL, d0b, dIH, dIL, dOH, dOL, cDec, x1H,
                                             x1L, 0);
    k_dec<1024, false><<<32, 256, 0, stream>>>((const int*)nullptr, (const float*)nullptr,
                                               x1H, x1L, d1WihH, d1WihL, d1WhhH, d1WhhL,
                                               d1b, dIH, dIL, dOH, dOL, cDec, x2H, x2L,
                                               1);
    k_gemm<32><<<dim3(391, 1, 1), 256, 0, stream>>>(x2H, x2L, predH, predL, predb, logits,
                                                    32, 50000, 1024, 0, 0, 0);
    k_lsm<<<32, 256, 0, stream>>>(logits, out, tok, t);
  }
}